// Round 2
// baseline (566.323 us; speedup 1.0000x reference)
//
#include <hip/hip_runtime.h>
#include <math.h>

#define HD 128

union F4 { float4 v; float f[4]; };

// ---------------- CSR build ----------------
__global__ void k_count(const int* __restrict__ dst, int* __restrict__ counts, int E){
  int e = blockIdx.x*256 + threadIdx.x;
  if (e < E) atomicAdd(&counts[dst[e]], 1);
}

__global__ void k_scan_block(const int* __restrict__ counts, int* __restrict__ scanTmp,
                             int* __restrict__ blockSums, int n){
  __shared__ int sm[256];
  int i = blockIdx.x*256 + threadIdx.x;
  int v = (i<n)?counts[i]:0;
  sm[threadIdx.x]=v; __syncthreads();
  for (int ofs=1; ofs<256; ofs<<=1){
    int t = (threadIdx.x>=ofs)?sm[threadIdx.x-ofs]:0;
    __syncthreads();
    sm[threadIdx.x]+=t;
    __syncthreads();
  }
  if (i<n) scanTmp[i]=sm[threadIdx.x];
  if (threadIdx.x==255) blockSums[blockIdx.x]=sm[255];
}

__global__ void k_scan_top(int* __restrict__ blockSums, int nb){
  __shared__ int sm[1024];
  int v = ((int)threadIdx.x<nb)?blockSums[threadIdx.x]:0;
  sm[threadIdx.x]=v; __syncthreads();
  for (int ofs=1; ofs<1024; ofs<<=1){
    int t = ((int)threadIdx.x>=ofs)?sm[threadIdx.x-ofs]:0;
    __syncthreads();
    sm[threadIdx.x]+=t;
    __syncthreads();
  }
  if ((int)threadIdx.x<nb) blockSums[threadIdx.x] = sm[threadIdx.x]-v; // exclusive
}

__global__ void k_scan_fin(const int* __restrict__ scanTmp, const int* __restrict__ blockSums,
                           const int* __restrict__ counts,
                           int* __restrict__ row_ptr, int* __restrict__ cursors, int n){
  int i = blockIdx.x*256 + threadIdx.x;
  if (i<n){
    int incl = scanTmp[i] + blockSums[blockIdx.x];
    row_ptr[i+1] = incl;
    cursors[i] = incl - counts[i];
  }
  if (i==0) row_ptr[0]=0;
}

// scatter edges into CSR order, materializing payload (src, etype, norm) so the
// per-row loop has a 2-deep (not 3-deep) dependent-load chain.
__global__ void k_scatter(const int* __restrict__ dst, const int* __restrict__ src,
                          const int* __restrict__ et, const float* __restrict__ norm,
                          int* __restrict__ cursors, int* __restrict__ src_s,
                          int* __restrict__ et_s, float* __restrict__ norm_s, int E){
  int e = blockIdx.x*256 + threadIdx.x;
  if (e<E){
    int p = atomicAdd(&cursors[dst[e]],1);
    src_s[p]=src[e]; et_s[p]=et[e]; norm_s[p]=norm[e];
  }
}

// ---------------- gather h0 = emb[node_ids] ----------------
__global__ void k_gather(const int* __restrict__ ids, const float4* __restrict__ emb4,
                         float4* __restrict__ h0, int nf4){
  int i = blockIdx.x*256+threadIdx.x;
  if (i<nf4){
    int row = i>>5, c = i&31;
    h0[i] = emb4[ids[row]*32 + c];
  }
}

// ---------------- edge aggregation (gather-CSR, one wave per dst row) ----------------
// layer1: W (R,32,4,4), out 128 per row. lane j handles cols j and j+64.
__global__ __launch_bounds__(256)
void k_edge1(const int* __restrict__ row_ptr, const int* __restrict__ src_s,
             const int* __restrict__ et_s, const float* __restrict__ norm_s,
             const float* __restrict__ h, const float* __restrict__ W,
             float* __restrict__ agg, int Nn){
  int wid = (blockIdx.x*256 + threadIdx.x)>>6;
  int lane = threadIdx.x & 63;
  if (wid >= Nn) return;
  int e0 = row_ptr[wid], e1 = row_ptr[wid+1];
  int b0 = lane>>2, o = lane&3;
  float acc0=0.f, acc1=0.f;
  for (int e=e0; e<e1; ++e){
    int s = src_s[e]; int r = et_s[e]; float nm = norm_s[e];
    const float* hp = &h[s*HD];
    const float* w  = &W[r*512];
    float4 hA = *(const float4*)&hp[b0*4];
    float4 hB = *(const float4*)&hp[(b0+16)*4];
    const float* wA = &w[b0*16 + o];
    const float* wB = &w[(b0+16)*16 + o];
    float m0 = hA.x*wA[0] + hA.y*wA[4] + hA.z*wA[8] + hA.w*wA[12];
    float m1 = hB.x*wB[0] + hB.y*wB[4] + hB.z*wB[8] + hB.w*wB[12];
    acc0 = fmaf(nm, m0, acc0);
    acc1 = fmaf(nm, m1, acc1);
  }
  agg[wid*HD + lane]      = acc0;
  agg[wid*HD + 64 + lane] = acc1;
}

// layer2: W (R,32,4,8), out 256 per row. lane j handles cols lane+64u, u=0..3.
__global__ __launch_bounds__(256)
void k_edge2(const int* __restrict__ row_ptr, const int* __restrict__ src_s,
             const int* __restrict__ et_s, const float* __restrict__ norm_s,
             const float* __restrict__ h, const float* __restrict__ W,
             float* __restrict__ agg, int Nn){
  int wid = (blockIdx.x*256 + threadIdx.x)>>6;
  int lane = threadIdx.x & 63;
  if (wid >= Nn) return;
  int e0 = row_ptr[wid], e1 = row_ptr[wid+1];
  int ob = lane>>3, o = lane&7;
  float acc[4] = {0.f,0.f,0.f,0.f};
  for (int e=e0; e<e1; ++e){
    int s = src_s[e]; int r = et_s[e]; float nm = norm_s[e];
    const float* hp = &h[s*HD];
    const float* w  = &W[r*1024];
    #pragma unroll
    for (int u=0; u<4; ++u){
      int b = ob + 8*u;
      float4 hv = *(const float4*)&hp[b*4];
      const float* wc = &w[b*32 + o];
      float m = hv.x*wc[0] + hv.y*wc[8] + hv.z*wc[16] + hv.w*wc[24];
      acc[u] = fmaf(nm, m, acc[u]);
    }
  }
  #pragma unroll
  for (int u=0; u<4; ++u) agg[wid*256 + u*64 + lane] = acc[u];
}

// ---------------- fused self-loop GEMM + epilogue ----------------
// C(M x NO) = A(M x 128) @ W(128 x NO)
// EPI=1: out = relu(C + agg + bias)                       (NO=128)
// EPI=2: full = C + agg + bias; split m|hp; z = m + sqrt(softplus(hp)+1e-8)*eps  (NO=256)
// A tile stored k-major transposed (As[kk*68+row], pad 68 keeps 16B alignment)
// so the inner loop is pure ds_read_b128: 1 broadcast A read + NG B reads per kk.
template<int NO, int EPI>
__global__ __launch_bounds__(256)
void k_gemm_fused(const float* __restrict__ A, const float* __restrict__ W,
                  const float* __restrict__ agg, const float* __restrict__ bias,
                  const float* __restrict__ eps, float* __restrict__ out, int M){
  constexpr int NG = NO/64;            // float4 col-groups per thread
  __shared__ __align__(16) float As[32*68];
  __shared__ __align__(16) float Bs[32*NO];
  const int tid = threadIdx.x;
  const int cg = tid & 15, rg = tid >> 4;   // thread -> cols cg*4+64g, rows rg*4+i
  const int rowBase = blockIdx.x*64;
  float acc[4][NG][4];
  #pragma unroll
  for (int i=0;i<4;++i)
    #pragma unroll
    for (int g=0;g<NG;++g)
      #pragma unroll
      for (int j=0;j<4;++j) acc[i][g][j]=0.f;

  for (int kt=0; kt<4; ++kt){
    // stage A tile transposed: 64 rows x 32 k  (512 float4 loads, 2/thread)
    #pragma unroll
    for (int it=0; it<2; ++it){
      int idx = it*256 + tid;
      int ar = idx>>3, ac4 = idx&7;
      int gr = rowBase + ar;
      F4 v; v.v = make_float4(0.f,0.f,0.f,0.f);
      if (gr < M) v.v = *(const float4*)&A[gr*HD + kt*32 + ac4*4];
      #pragma unroll
      for (int j=0;j<4;++j) As[(ac4*4+j)*68 + ar] = v.f[j];
    }
    // stage W tile: 32 k-rows x NO cols (linear, b128 in and out)
    #pragma unroll
    for (int it=0; it<(32*NO/4)/256; ++it){
      int idx = it*256 + tid;
      int wr = idx/(NO/4), wc4 = idx%(NO/4);
      *(float4*)&Bs[wr*NO + wc4*4] = *(const float4*)&W[(kt*32+wr)*NO + wc4*4];
    }
    __syncthreads();
    #pragma unroll 4
    for (int kk=0; kk<32; ++kk){
      F4 a; a.v = *(const float4*)&As[kk*68 + rg*4];
      F4 b[NG];
      #pragma unroll
      for (int g=0; g<NG; ++g) b[g].v = *(const float4*)&Bs[kk*NO + cg*4 + 64*g];
      #pragma unroll
      for (int i=0;i<4;++i)
        #pragma unroll
        for (int g=0;g<NG;++g)
          #pragma unroll
          for (int j=0;j<4;++j)
            acc[i][g][j] = fmaf(a.f[i], b[g].f[j], acc[i][g][j]);
    }
    __syncthreads();
  }

  #pragma unroll
  for (int i=0;i<4;++i){
    int r = rowBase + rg*4 + i;
    if (r >= M) continue;
    if (EPI==1){
      #pragma unroll
      for (int g=0;g<NG;++g){
        int col0 = cg*4 + 64*g;
        F4 ag; ag.v = *(const float4*)&agg[r*NO + col0];
        F4 bs; bs.v = *(const float4*)&bias[col0];
        F4 o;
        #pragma unroll
        for (int j=0;j<4;++j) o.f[j] = fmaxf(acc[i][g][j] + ag.f[j] + bs.f[j], 0.f);
        *(float4*)&out[r*NO + col0] = o.v;
      }
    } else {
      #pragma unroll
      for (int g=0;g<2;++g){
        int col0 = cg*4 + 64*g;
        F4 agm;  agm.v  = *(const float4*)&agg[r*256 + col0];
        F4 aghp; aghp.v = *(const float4*)&agg[r*256 + col0 + 128];
        F4 bsm;  bsm.v  = *(const float4*)&bias[col0];
        F4 bshp; bshp.v = *(const float4*)&bias[col0 + 128];
        F4 ep;   ep.v   = *(const float4*)&eps[r*128 + col0];
        F4 z;
        #pragma unroll
        for (int j=0;j<4;++j){
          float m  = acc[i][g][j]   + agm.f[j]  + bsm.f[j];
          float hp = acc[i][g+2][j] + aghp.f[j] + bshp.f[j];
          float sp = fmaxf(hp, 0.f) + log1pf(expf(-fabsf(hp)));  // stable softplus
          z.f[j] = fmaf(sqrtf(sp + 1e-8f), ep.f[j], m);
        }
        *(float4*)&out[r*128 + col0] = z.v;
      }
    }
  }
}

extern "C" void kernel_launch(void* const* d_in, const int* in_sizes, int n_in,
                              void* d_out, int out_size, void* d_ws, size_t ws_size,
                              hipStream_t stream){
  (void)n_in; (void)out_size; (void)ws_size;
  const int*   node_ids = (const int*)d_in[0];
  const int*   src  = (const int*)d_in[1];
  const int*   dst  = (const int*)d_in[2];
  const int*   et   = (const int*)d_in[3];
  const float* norm = (const float*)d_in[4];
  const float* emb  = (const float*)d_in[5];
  const float* W1   = (const float*)d_in[6];
  const float* lw1  = (const float*)d_in[7];
  const float* b1   = (const float*)d_in[8];
  const float* W2   = (const float*)d_in[9];
  const float* lw2  = (const float*)d_in[10];
  const float* b2   = (const float*)d_in[11];
  const float* eps  = (const float*)d_in[12];
  float* out = (float*)d_out;

  const int N = in_sizes[0];
  const int E = in_sizes[1];

  // workspace layout (bytes):
  // [0, 2*szNH)        : h0 (first szNH; dead after gemm1) / agg2 (full 2*szNH)
  // [2*szNH, 3*szNH)   : h1
  // [3*szNH, 4*szNH)   : agg1
  // [4*szNH, ...)      : CSR integer scratch + sorted edge payload
  char* w = (char*)d_ws;
  size_t szNH = (size_t)N*HD*sizeof(float);
  float* h0   = (float*)(w);
  float* agg2 = (float*)(w);
  float* h1   = (float*)(w + 2*szNH);
  float* agg1 = (float*)(w + 3*szNH);
  char*  ip   = w + 4*szNH;
  int*   counts    = (int*)ip;
  int*   scanTmp   = counts + N;
  int*   row_ptr   = scanTmp + N;
  int*   cursors   = row_ptr + (N+1);
  int*   blockSums = cursors + N;
  int*   src_s     = blockSums + 1024;
  int*   et_s      = src_s + E;
  float* norm_s    = (float*)(et_s + E);

  hipMemsetAsync(counts, 0, (size_t)N*sizeof(int), stream);

  int nb_e    = (E+255)/256;
  int nb_scan = (N+255)/256;   // 391 (<1024, single-level top scan ok)

  k_gather<<<(N*32+255)/256, 256, 0, stream>>>(node_ids, (const float4*)emb, (float4*)h0, N*32);
  k_count<<<nb_e, 256, 0, stream>>>(dst, counts, E);
  k_scan_block<<<nb_scan, 256, 0, stream>>>(counts, scanTmp, blockSums, N);
  k_scan_top<<<1, 1024, 0, stream>>>(blockSums, nb_scan);
  k_scan_fin<<<nb_scan, 256, 0, stream>>>(scanTmp, blockSums, counts, row_ptr, cursors, N);
  k_scatter<<<nb_e, 256, 0, stream>>>(dst, src, et, norm, cursors, src_s, et_s, norm_s, E);

  int nb_rows = (N+3)/4;      // one 64-lane wave per dst row, 4 waves/block
  int nb_gemm = (N+63)/64;

  k_edge1<<<nb_rows, 256, 0, stream>>>(row_ptr, src_s, et_s, norm_s, h0, W1, agg1, N);
  k_gemm_fused<128,1><<<nb_gemm, 256, 0, stream>>>(h0, lw1, agg1, b1, nullptr, h1, N);
  k_edge2<<<nb_rows, 256, 0, stream>>>(row_ptr, src_s, et_s, norm_s, h1, W2, agg2, N);
  k_gemm_fused<256,2><<<nb_gemm, 256, 0, stream>>>(h1, lw2, agg2, b2, eps, out, N);
}